// Round 2
// baseline (265.623 us; speedup 1.0000x reference)
//
#include <hip/hip_runtime.h>
#include <math.h>

#define NHEADS 8
#define DH 32
#define NB 64
#define TK 192      // LDS-staged keys per (batch,head); overflow falls back to global reads
#define LDK 33      // padded LDS row stride (bank-conflict-free)
#define PROJ_ROWS 8
#define OP_ROWS 8

// ---------------- batch range computation (sorted indices -> start offsets) ----
__global__ void ranges_kernel(const int* __restrict__ didx, int Nd,
                              const int* __restrict__ ridx, int Nr,
                              int* __restrict__ dstart, int* __restrict__ rstart)
{
    int t = threadIdx.x;
    if (t <= NB) {
        int lo = 0, hi = Nd;
        while (lo < hi) { int mid = (lo + hi) >> 1; if (didx[mid] < t) lo = mid + 1; else hi = mid; }
        dstart[t] = lo;
    } else if (t >= 128 && t <= 128 + NB) {
        int v = t - 128;
        int lo = 0, hi = Nr;
        while (lo < hi) { int mid = (lo + hi) >> 1; if (ridx[mid] < v) lo = mid + 1; else hi = mid; }
        rstart[v] = lo;
    }
}

// ---------------- fused Q/K/V projection, head-major outputs [H][N][DH] --------
__global__ __launch_bounds__(256) void proj3_kernel(
    const float* __restrict__ X, int N,
    const float* __restrict__ Wq, const float* __restrict__ Wk, const float* __restrict__ Wv,
    float* __restrict__ Qh, float* __restrict__ Kh, float* __restrict__ Vh)
{
    __shared__ float xs[PROJ_ROWS][128];
    int row0 = blockIdx.x * PROJ_ROWS;
    int t = threadIdx.x;
    for (int i = t; i < PROJ_ROWS * 128; i += 256)
        xs[i >> 7][i & 127] = X[(size_t)row0 * 128 + i];
    __syncthreads();

    float aq[PROJ_ROWS], ak[PROJ_ROWS], av[PROJ_ROWS];
#pragma unroll
    for (int r = 0; r < PROJ_ROWS; ++r) { aq[r] = 0.f; ak[r] = 0.f; av[r] = 0.f; }

    for (int k = 0; k < 128; ++k) {
        float wq = Wq[k * 256 + t];
        float wk = Wk[k * 256 + t];
        float wv = Wv[k * 256 + t];
#pragma unroll
        for (int r = 0; r < PROJ_ROWS; ++r) {
            float x = xs[r][k];
            aq[r] = fmaf(x, wq, aq[r]);
            ak[r] = fmaf(x, wk, ak[r]);
            av[r] = fmaf(x, wv, av[r]);
        }
    }

    int h = t >> 5, d = t & 31;
#pragma unroll
    for (int r = 0; r < PROJ_ROWS; ++r) {
        size_t o = ((size_t)h * N + (row0 + r)) * DH + d;
        Qh[o] = aq[r];
        Kh[o] = ak[r];
        Vh[o] = av[r];
    }
}

// ---------------- per-(batch,head) masked attention ---------------------------
__device__ __forceinline__ float kv_fetch(const float* __restrict__ g, const float* l,
                                          int j, int d)
{
    return (j < TK) ? l[j * LDK + d] : g[(size_t)j * DH + d];
}

__global__ __launch_bounds__(256) void attn_kernel(
    const float* __restrict__ Qh, const float* __restrict__ Kh, const float* __restrict__ Vh,
    const int* __restrict__ qstart, const int* __restrict__ kstart,
    int Nq, int Nk, float scale, float* __restrict__ ctx)
{
    __shared__ float Kl[TK * LDK];
    __shared__ float Vl[TK * LDK];
    int b = blockIdx.x, h = blockIdx.y;
    int q0 = qstart[b], nq = qstart[b + 1] - q0;
    int k0 = kstart[b], nk = kstart[b + 1] - k0;
    if (nq <= 0) return;

    int t = threadIdx.x, wave = t >> 6, lane = t & 63;
    const float* Qb = Qh + (size_t)h * Nq * DH;
    const float* Kb = Kh + ((size_t)h * Nk + k0) * DH;
    const float* Vb = Vh + ((size_t)h * Nk + k0) * DH;

    int nstage = nk < TK ? nk : TK;
    for (int i = t; i < nstage * DH; i += 256) {
        int j = i >> 5, d = i & 31;
        Kl[j * LDK + d] = Kb[i];
        Vl[j * LDK + d] = Vb[i];
    }
    __syncthreads();

    int d = lane & 31, s2 = lane >> 5;
    for (int qi = wave; qi < nq; qi += 4) {
        float q[DH];
#pragma unroll
        for (int e = 0; e < DH; ++e) q[e] = Qb[(size_t)(q0 + qi) * DH + e];

        float m = -1e30f, l = 0.f, oacc = 0.f;
        for (int c0 = 0; c0 < nk; c0 += 256) {
            int cn = nk - c0; if (cn > 256) cn = 256;

            float sc[4];
            float mloc = -1e30f;
#pragma unroll
            for (int rr = 0; rr < 4; ++rr) {
                int jr = lane + 64 * rr;
                float s = -1e30f;
                if (jr < cn) {
                    s = 0.f;
#pragma unroll
                    for (int e = 0; e < DH; ++e)
                        s = fmaf(q[e], kv_fetch(Kb, Kl, c0 + jr, e), s);
                    s *= scale;
                }
                sc[rr] = s;
                mloc = fmaxf(mloc, s);
            }
#pragma unroll
            for (int off = 32; off >= 1; off >>= 1)
                mloc = fmaxf(mloc, __shfl_xor(mloc, off));

            float mnew = fmaxf(m, mloc);
            float corr = __expf(m - mnew);
            float lloc = 0.f;
#pragma unroll
            for (int rr = 0; rr < 4; ++rr) {
                int jr = lane + 64 * rr;
                sc[rr] = (jr < cn) ? __expf(sc[rr] - mnew) : 0.f;
                lloc += sc[rr];
            }
#pragma unroll
            for (int off = 32; off >= 1; off >>= 1)
                lloc += __shfl_xor(lloc, off);

            l = l * corr + lloc;
            oacc *= corr;
            m = mnew;

#pragma unroll
            for (int rr = 0; rr < 4; ++rr) {
                if (rr * 64 >= cn) break;
                for (int jj = 0; jj < 32; ++jj) {
                    int jrel = rr * 64 + 2 * jj + s2;
                    float p = __shfl(sc[rr], 2 * jj + s2);
                    if (jrel < cn)
                        oacc = fmaf(p, kv_fetch(Vb, Vl, c0 + jrel, d), oacc);
                }
            }
        }

        float osum = oacc + __shfl_xor(oacc, 32);
        float linv = 1.0f / l;
        if (lane < DH)
            ctx[(size_t)(q0 + qi) * (NHEADS * DH) + h * DH + d] = osum * linv;
    }
}

// ---------------- output projection: out = ctx @ Wo + bo ----------------------
__global__ __launch_bounds__(128) void outproj_kernel(
    const float* __restrict__ ctx, const float* __restrict__ Wo,
    const float* __restrict__ bo, float* __restrict__ out)
{
    __shared__ float cs[OP_ROWS][256];
    int row0 = blockIdx.x * OP_ROWS;
    int t = threadIdx.x;
    for (int i = t; i < OP_ROWS * 256; i += 128)
        cs[i >> 8][i & 255] = ctx[(size_t)row0 * 256 + i];
    __syncthreads();

    float acc[OP_ROWS];
    float bias = bo[t];
#pragma unroll
    for (int r = 0; r < OP_ROWS; ++r) acc[r] = bias;

    for (int k = 0; k < 256; ++k) {
        float w = Wo[k * 128 + t];
#pragma unroll
        for (int r = 0; r < OP_ROWS; ++r)
            acc[r] = fmaf(cs[r][k], w, acc[r]);
    }
#pragma unroll
    for (int r = 0; r < OP_ROWS; ++r)
        out[(size_t)(row0 + r) * 128 + t] = acc[r];
}

extern "C" void kernel_launch(void* const* d_in, const int* in_sizes, int n_in,
                              void* d_out, int out_size, void* d_ws, size_t ws_size,
                              hipStream_t stream)
{
    const float* drug = (const float*)d_in[0];
    const float* rna  = (const float*)d_in[1];
    const float* Wq_d = (const float*)d_in[2];
    const float* Wk_r = (const float*)d_in[3];
    const float* Wv_r = (const float*)d_in[4];
    const float* Wo_d = (const float*)d_in[5];
    const float* bo_d = (const float*)d_in[6];
    const float* Wq_r = (const float*)d_in[7];
    const float* Wk_d = (const float*)d_in[8];
    const float* Wv_d = (const float*)d_in[9];
    const float* Wo_r = (const float*)d_in[10];
    const float* bo_r = (const float*)d_in[11];
    const int* didx = (const int*)d_in[12];
    const int* ridx = (const int*)d_in[13];
    int Nd = in_sizes[12], Nr = in_sizes[13];

    float* ws = (float*)d_ws;
    size_t SD = (size_t)Nd * 256, SR = (size_t)Nr * 256;
    float* Qd = ws;        float* Kd = Qd + SD;  float* Vd = Kd + SD;
    float* Qr = Vd + SD;   float* Kr = Qr + SR;  float* Vr = Kr + SR;
    float* Cd = Vr + SR;   float* Cr = Cd + SD;
    int* dstart = (int*)(Cr + SR);
    int* rstart = dstart + (NB + 1);

    float* out = (float*)d_out;
    const float scale = 0.17677669529663689f;  // 1/sqrt(32)

    ranges_kernel<<<1, 256, 0, stream>>>(didx, Nd, ridx, Nr, dstart, rstart);
    proj3_kernel<<<Nd / PROJ_ROWS, 256, 0, stream>>>(drug, Nd, Wq_d, Wk_d, Wv_d, Qd, Kd, Vd);
    proj3_kernel<<<Nr / PROJ_ROWS, 256, 0, stream>>>(rna,  Nr, Wq_r, Wk_r, Wv_r, Qr, Kr, Vr);
    attn_kernel<<<dim3(NB, NHEADS), 256, 0, stream>>>(Qd, Kr, Vr, dstart, rstart, Nd, Nr, scale, Cd);
    attn_kernel<<<dim3(NB, NHEADS), 256, 0, stream>>>(Qr, Kd, Vd, rstart, dstart, Nr, Nd, scale, Cr);
    outproj_kernel<<<Nd / OP_ROWS, 128, 0, stream>>>(Cd, Wo_d, bo_d, out);
    outproj_kernel<<<Nr / OP_ROWS, 128, 0, stream>>>(Cr, Wo_r, bo_r, out + (size_t)Nd * 128);
}

// Round 6
// 150.060 us; speedup vs baseline: 1.7701x; 1.7701x over previous
//
#include <hip/hip_runtime.h>
#include <math.h>

#define NHEADS 8
#define DH 32
#define NB 64
#define PROJ_ROWS 16
#define OP_ROWS 8

// ---------------- batch range computation (sorted indices -> start offsets) ----
__global__ void ranges_kernel(const int* __restrict__ didx, int Nd,
                              const int* __restrict__ ridx, int Nr,
                              int* __restrict__ dstart, int* __restrict__ rstart)
{
    int t = threadIdx.x;
    if (t <= NB) {
        int lo = 0, hi = Nd;
        while (lo < hi) { int mid = (lo + hi) >> 1; if (didx[mid] < t) lo = mid + 1; else hi = mid; }
        dstart[t] = lo;
    } else if (t >= 128 && t <= 128 + NB) {
        int v = t - 128;
        int lo = 0, hi = Nr;
        while (lo < hi) { int mid = (lo + hi) >> 1; if (ridx[mid] < v) lo = mid + 1; else hi = mid; }
        rstart[v] = lo;
    }
}

// ---------------- fused Q/K/V projection ---------------------------------------
// Q out: [H][N][32] pre-scaled by 1/sqrt(DH).  K out TRANSPOSED: [H][32][N].
// V out: [H][N][32].
__global__ __launch_bounds__(256) void proj3_kernel(
    const float* __restrict__ X, int N, float scale,
    const float* __restrict__ Wq, const float* __restrict__ Wk, const float* __restrict__ Wv,
    float* __restrict__ Qh, float* __restrict__ Kt, float* __restrict__ Vh)
{
    __shared__ float xs[PROJ_ROWS][128];
    int row0 = blockIdx.x * PROJ_ROWS;
    int t = threadIdx.x;
    for (int i = t; i < PROJ_ROWS * 128; i += 256)
        xs[i >> 7][i & 127] = X[(size_t)row0 * 128 + i];
    __syncthreads();

    float aq[PROJ_ROWS], ak[PROJ_ROWS], av[PROJ_ROWS];
#pragma unroll
    for (int r = 0; r < PROJ_ROWS; ++r) { aq[r] = 0.f; ak[r] = 0.f; av[r] = 0.f; }

    for (int k = 0; k < 128; ++k) {
        float wq = Wq[k * 256 + t];
        float wk = Wk[k * 256 + t];
        float wv = Wv[k * 256 + t];
#pragma unroll
        for (int r = 0; r < PROJ_ROWS; ++r) {
            float x = xs[r][k];
            aq[r] = fmaf(x, wq, aq[r]);
            ak[r] = fmaf(x, wk, ak[r]);
            av[r] = fmaf(x, wv, av[r]);
        }
    }

    int h = t >> 5, d = t & 31;
#pragma unroll
    for (int r = 0; r < PROJ_ROWS; ++r) {
        size_t o = ((size_t)h * N + (row0 + r)) * DH + d;
        Qh[o] = aq[r] * scale;
        Vh[o] = av[r];
        Kt[(size_t)t * N + (row0 + r)] = ak[r];   // [H*32][N] transposed
    }
}

// ---------------- masked attention: one wave per (query row, head) -------------
__global__ __launch_bounds__(256) void attn_v2(
    const float* __restrict__ Qh,   // [H][Nq][32], pre-scaled
    const float* __restrict__ Kt,   // [H][32][Nk]
    const float* __restrict__ Vh,   // [H][Nk][32]
    const int* __restrict__ qidx,   // [Nq] sorted batch id per query row
    const int* __restrict__ kstart, // [NB+1] key-side batch offsets
    int Nq, int Nk, float* __restrict__ ctx)
{
    __shared__ float p_lds[4][64];
    int wave = threadIdx.x >> 6, lane = threadIdx.x & 63;
    int row = blockIdx.x * 4 + wave;
    int h = blockIdx.y;
    if (row >= Nq) return;

    int b = qidx[row];
    int k0 = kstart[b], nk = kstart[b + 1] - k0;

    const float* q_ptr = Qh + ((size_t)h * Nq + row) * DH;
    float q[DH];
#pragma unroll
    for (int e4 = 0; e4 < 8; ++e4) {
        float4 v = ((const float4*)q_ptr)[e4];
        q[4 * e4 + 0] = v.x; q[4 * e4 + 1] = v.y;
        q[4 * e4 + 2] = v.z; q[4 * e4 + 3] = v.w;
    }

    const float* Ktb = Kt + (size_t)h * DH * Nk + k0;      // row e: Ktb[e*Nk + j]
    const float* Vb  = Vh + ((size_t)h * Nk + k0) * DH;

    float m = -1e30f, l = 0.f, oacc = 0.f;
    int d = lane & 31, j2 = lane >> 5;

    for (int c0 = 0; c0 < nk; c0 += 64) {
        int jk = c0 + lane;
        bool valid = jk < nk;
        int jkc = valid ? jk : (nk - 1);

        float s0 = 0.f, s1 = 0.f;
#pragma unroll
        for (int e = 0; e < DH; e += 2) {
            s0 = fmaf(q[e],     Ktb[(size_t)e * Nk + jkc],       s0);
            s1 = fmaf(q[e + 1], Ktb[(size_t)(e + 1) * Nk + jkc], s1);
        }
        float s = valid ? (s0 + s1) : -1e30f;

        float mloc = s;
#pragma unroll
        for (int off = 32; off >= 1; off >>= 1)
            mloc = fmaxf(mloc, __shfl_xor(mloc, off));
        float mnew = fmaxf(m, mloc);
        float corr = __expf(m - mnew);
        float p = valid ? __expf(s - mnew) : 0.f;
        float lloc = p;
#pragma unroll
        for (int off = 32; off >= 1; off >>= 1)
            lloc += __shfl_xor(lloc, off);
        l = l * corr + lloc;
        oacc *= corr;
        m = mnew;

        p_lds[wave][lane] = p;
        asm volatile("s_waitcnt lgkmcnt(0)" ::: "memory");

        // PV: lanes re-role as (j2, d); p broadcast from LDS, V reads coalesced
#pragma unroll 8
        for (int jj = 0; jj < 32; ++jj) {
            int j = jj * 2 + j2;
            int jc = (c0 + j < nk) ? (c0 + j) : (nk - 1);
            float pv = p_lds[wave][j];
            float vv = Vb[(size_t)jc * DH + d];
            oacc = fmaf(pv, vv, oacc);
        }
    }

    float osum = oacc + __shfl_xor(oacc, 32);
    if (lane < DH)
        ctx[(size_t)row * (NHEADS * DH) + h * DH + d] = osum / l;
}

// ---------------- output projection: out = ctx @ Wo + bo -----------------------
__global__ __launch_bounds__(256) void outproj_kernel(
    const float* __restrict__ ctx, const float* __restrict__ Wo,
    const float* __restrict__ bo, float* __restrict__ out)
{
    __shared__ float cs[OP_ROWS][256];
    int row0 = blockIdx.x * OP_ROWS;
    int t = threadIdx.x;
    for (int i = t; i < OP_ROWS * 256; i += 256)
        cs[i >> 8][i & 255] = ctx[(size_t)row0 * 256 + i];
    __syncthreads();

    int c = t & 127, rh = t >> 7;          // rh in {0,1}: rows 0..3 / 4..7
    float bias = bo[c];
    float acc[4];
#pragma unroll
    for (int r = 0; r < 4; ++r) acc[r] = bias;

    for (int k = 0; k < 256; ++k) {
        float w = Wo[k * 128 + c];
#pragma unroll
        for (int r = 0; r < 4; ++r)
            acc[r] = fmaf(cs[rh * 4 + r][k], w, acc[r]);
    }
#pragma unroll
    for (int r = 0; r < 4; ++r)
        out[(size_t)(row0 + rh * 4 + r) * 128 + c] = acc[r];
}

extern "C" void kernel_launch(void* const* d_in, const int* in_sizes, int n_in,
                              void* d_out, int out_size, void* d_ws, size_t ws_size,
                              hipStream_t stream)
{
    const float* drug = (const float*)d_in[0];
    const float* rna  = (const float*)d_in[1];
    const float* Wq_d = (const float*)d_in[2];
    const float* Wk_r = (const float*)d_in[3];
    const float* Wv_r = (const float*)d_in[4];
    const float* Wo_d = (const float*)d_in[5];
    const float* bo_d = (const float*)d_in[6];
    const float* Wq_r = (const float*)d_in[7];
    const float* Wk_d = (const float*)d_in[8];
    const float* Wv_d = (const float*)d_in[9];
    const float* Wo_r = (const float*)d_in[10];
    const float* bo_r = (const float*)d_in[11];
    const int* didx = (const int*)d_in[12];
    const int* ridx = (const int*)d_in[13];
    int Nd = in_sizes[12], Nr = in_sizes[13];

    float* ws = (float*)d_ws;
    size_t SD = (size_t)Nd * 256, SR = (size_t)Nr * 256;
    float* Qd  = ws;        float* Ktd = Qd + SD;   float* Vd = Ktd + SD;
    float* Qr  = Vd + SD;   float* Ktr = Qr + SR;   float* Vr = Ktr + SR;
    float* Cd  = Vr + SR;   float* Cr  = Cd + SD;
    int* dstart = (int*)(Cr + SR);
    int* rstart = dstart + (NB + 1);

    float* out = (float*)d_out;
    const float scale = 0.17677669529663689f;  // 1/sqrt(32)

    ranges_kernel<<<1, 256, 0, stream>>>(didx, Nd, ridx, Nr, dstart, rstart);
    proj3_kernel<<<Nd / PROJ_ROWS, 256, 0, stream>>>(drug, Nd, scale, Wq_d, Wk_d, Wv_d, Qd, Ktd, Vd);
    proj3_kernel<<<Nr / PROJ_ROWS, 256, 0, stream>>>(rna,  Nr, scale, Wq_r, Wk_r, Wv_r, Qr, Ktr, Vr);
    attn_v2<<<dim3((Nd + 3) / 4, NHEADS), 256, 0, stream>>>(Qd, Ktr, Vr, didx, rstart, Nd, Nr, Cd);
    attn_v2<<<dim3((Nr + 3) / 4, NHEADS), 256, 0, stream>>>(Qr, Ktd, Vd, ridx, dstart, Nr, Nd, Cr);
    outproj_kernel<<<Nd / OP_ROWS, 256, 0, stream>>>(Cd, Wo_d, bo_d, out);
    outproj_kernel<<<Nr / OP_ROWS, 256, 0, stream>>>(Cr, Wo_r, bo_r, out + (size_t)Nd * 128);
}